// Round 2
// baseline (149.073 us; speedup 1.0000x reference)
//
#include <hip/hip_runtime.h>

// Problem constants (match the JAX reference).
#define BB     16
#define QQ     2048
#define NCLS   2
#define DBOX   6
#define TT     1024
#define ROWS   (BB * QQ)          // 32768 (b,q) rows
#define TPB    256                // threads per block
#define TPT    4                  // targets per thread: 256*4 = 1024 = TT
#define RPB    16                 // rows per block: grid = 32768/16 = 2048 blocks

// clang vector type — accepted by __builtin_nontemporal_store (HIP float4 is not).
typedef float v4f __attribute__((ext_vector_type(4)));

__global__ __launch_bounds__(TPB) void hungarian_cost_kernel(
    const float* __restrict__ logits,   // (ROWS, NCLS) f32
    const float* __restrict__ boxes,    // (ROWS, DBOX) f32
    const int*   __restrict__ labels,   // (TT,) int32
    const float* __restrict__ tboxes,   // (TT, DBOX) f32
    float*       __restrict__ out)      // (ROWS, TT) f32
{
    const int tid  = threadIdx.x;
    const int t0   = tid * TPT;
    const int row0 = blockIdx.x * RPB;

    // Per-row staging: [0..5] = query box, [6] = p0, [7] = p1-p0.
    // 16 rows x 8 floats = 512 B. All later reads are wave-uniform -> broadcast,
    // zero bank conflicts.
    __shared__ float srow[RPB][8];

    if (tid < RPB) {
        const int row = row0 + tid;
        const float l0  = logits[row * NCLS + 0];
        const float l1  = logits[row * NCLS + 1];
        const float e0  = __expf(l0);
        const float e1  = __expf(l1);
        const float inv = 1.0f / (e0 + e1);
#pragma unroll
        for (int d = 0; d < DBOX; ++d) srow[tid][d] = boxes[row * DBOX + d];
        srow[tid][6] = e0 * inv;          // p0
        srow[tid][7] = (e1 - e0) * inv;   // p1 - p0
    }

    // --- Preload this thread's 4 targets into registers (one time) ---
    float tb[TPT][DBOX];
    float w[TPT];
#pragma unroll
    for (int j = 0; j < TPT; ++j) {
        const int t = t0 + j;
#pragma unroll
        for (int d = 0; d < DBOX; ++d) tb[j][d] = tboxes[t * DBOX + d];
        w[j] = (float)labels[t];          // label in {0,1} -> selector weight
    }

    __syncthreads();

    // Hot loop: no global loads, no transcendentals — LDS broadcast + VALU + NT store.
    float* optr = out + (size_t)row0 * TT + t0;   // 16B aligned (t0 % 4 == 0)
#pragma unroll 4
    for (int r = 0; r < RPB; ++r) {
        float qb[DBOX];
#pragma unroll
        for (int d = 0; d < DBOX; ++d) qb[d] = srow[r][d];
        const float p0  = srow[r][6];
        const float d10 = srow[r][7];

        float c[TPT];
#pragma unroll
        for (int j = 0; j < TPT; ++j) {
            float s = 0.0f;
#pragma unroll
            for (int d = 0; d < DBOX; ++d) s += fabsf(qb[d] - tb[j][d]);
            // c = 5*L1 - (p0 + w*(p1-p0))
            c[j] = fmaf(5.0f, s, -fmaf(w[j], d10, p0));
        }

        v4f v = { c[0], c[1], c[2], c[3] };
        __builtin_nontemporal_store(v, reinterpret_cast<v4f*>(optr));
        optr += TT;
    }
}

extern "C" void kernel_launch(void* const* d_in, const int* in_sizes, int n_in,
                              void* d_out, int out_size, void* d_ws, size_t ws_size,
                              hipStream_t stream) {
    const float* logits = (const float*)d_in[0];   // (B,Q,NCLS) f32
    const float* boxes  = (const float*)d_in[1];   // (B,Q,DBOX) f32
    const int*   labels = (const int*)  d_in[2];   // (T,) int32
    const float* tboxes = (const float*)d_in[3];   // (T,DBOX) f32
    float*       out    = (float*)d_out;           // (B,Q,T) f32

    const int grid = ROWS / RPB;  // 2048
    hungarian_cost_kernel<<<grid, TPB, 0, stream>>>(logits, boxes, labels, tboxes, out);
}